// Round 7
// baseline (157.577 us; speedup 1.0000x reference)
//
#include <hip/hip_runtime.h>
#include <math.h>

#define BB 4
#define C 64
#define O 64
#define H 128
#define W 128
#define K2 9
#define HW (H*W)
#define NOFF 36

typedef __bf16 bf16;
typedef bf16 bf16x8 __attribute__((ext_vector_type(8)));
typedef float f32x4 __attribute__((ext_vector_type(4)));
typedef unsigned short u16x8 __attribute__((ext_vector_type(8)));
typedef unsigned int u32x4 __attribute__((ext_vector_type(4)));

#define BSTR 55          /* bufF row stride (fp32 conv outputs) */
#define VSTR 36          /* valF row stride (fp32) */
/* R19: 32-px / 256-thr / 4-wave blocks (R17 geometry) but the main deform
 * loop is IN-REGISTER: each lane gathers its own 4 corners for exactly the
 * channels its MFMA b-frag needs (g*32+q4*8..+7 of pixel nt*16+n16), lerps
 * in regs, feeds MFMA directly.  val LDS staging + its 6 barriers GONE.
 * Main loop has ZERO barriers; 5 barriers total in kernel (was ~10).
 * Cost: lerp VALU x2 and corner L2 reads x2 (2 waves per pixel) -- L2
 * bytes measured non-binding in R15.
 * LDS overlay (19,968 B):
 *   [0 .. 13,056)  stage 102 rows swz (conv; dies at conv barrier)
 *   [0 ..  7,040)  bufF[32][55]f32   (conv out; dies in precompute)
 *   [0 ..  9,216)  valF[64][36]f32   (final epilogue only)
 *   [13,056..19,968) buf2a/b/c u32[576] (params; precompute -> main, RO)
 * 8 x 19,968 = 159,744 <= 160 KiB -> 8 blocks/CU x 4 waves = 32 waves/CU.
 * launch_bounds(256,8): VGPR cap 64. */
#define B2A_OFF 13056
#define B2B_OFF 15360
#define B2C_OFF 17664
#define SMEM_BYTES 19968
#define WFRAG 18432      /* bf16 per conv-half / group: 9*4*64*8 */
#define NW_TOTAL 73728

__device__ inline unsigned short f2h_bits(float f) {
  _Float16 h = (_Float16)f;
  return __builtin_bit_cast(unsigned short, h);
}
__device__ inline float h2f(unsigned short u) {
  return (float)__builtin_bit_cast(_Float16, u);
}
/* swizzled LDS offset in bf16 units: row*64 + (chunk^(row&7))*8 */
__device__ inline int soff(int row, int chunk) {
  return row * 64 + ((chunk ^ (row & 7)) * 8);
}

// ---------------------------------------------------------------------------
// K1 (validated R6-R17): NCHW fp32 -> NHWC bf16 transpose (1024 blocks) +
// weight swizzle to MFMA a-frag order (first 288 blocks).
//  frag[(ph*9+kk)*4+to][lane][j] = Wrow[m=to*16+(lane&15)][u=kk*32+(lane>>4)*8+j]
//  K order u = tap*32 + c'.  wfC: m<36 w_off, m<54 w_mask, else 0.
// ---------------------------------------------------------------------------
__global__ __launch_bounds__(256) void prep_all(
    const float* __restrict__ x, const float* __restrict__ w_main,
    const float* __restrict__ w_off, const float* __restrict__ w_mask,
    unsigned short* __restrict__ xT16, bf16* __restrict__ wfC,
    bf16* __restrict__ wfM) {
  __shared__ float tile[64][69];
  int tid = threadIdx.x;
  int b = blockIdx.x >> 8;
  int p0 = (blockIdx.x & 255) * 64;
#pragma unroll
  for (int it = 0; it < 4; ++it) {
    int c = it * 16 + (tid >> 4);
    int p4 = (tid & 15) * 4;
    *(f32x4*)&tile[c][p4] =
        *(const f32x4*)(x + (size_t)(b * C + c) * HW + p0 + p4);
  }
  __syncthreads();
#pragma unroll
  for (int it = 0; it < 2; ++it) {
    int t = it * 256 + tid;
    int p = t >> 3;
    int h8 = t & 7;
    u16x8 o;
#pragma unroll
    for (int j = 0; j < 8; ++j) {
      bf16 v = (bf16)tile[h8 * 8 + j][p];
      o[j] = __builtin_bit_cast(unsigned short, v);
    }
    *(u16x8*)&xT16[(size_t)(b * HW + p0 + p) * C + h8 * 8] = o;
  }
  int i = blockIdx.x * 256 + tid;
  if (i < NW_TOTAL) {
    int which = (i >= 36864);
    int ii = which ? i - 36864 : i;
    int j = ii & 7;
    int l = (ii >> 3) & 63;
    int rest = ii >> 9;
    int to = rest & 3;
    int kk = (rest >> 2) % 9;
    int ph = (rest >> 2) / 9;
    int m = to * 16 + (l & 15);
    int u = kk * 32 + (l >> 4) * 8 + j;
    int tap = u >> 5;
    int c1 = u & 31;
    if (!which) {
      int c = ph * 32 + c1;
      float v = (m < NOFF) ? w_off[(m * C + c) * K2 + tap]
                : (m < 54) ? w_mask[((m - NOFF) * C + c) * K2 + tap]
                           : 0.f;
      wfC[ii] = (bf16)v;
    } else {
      wfM[ii] = (bf16)w_main[(m * C + ph * 32 + c1) * K2 + tap];
    }
  }
}

// ---------------------------------------------------------------------------
// K2: fused deform, 32-px tiles x 256 threads (4 waves), grid 2048.
// Conv (unchanged R17): wave wv=to, both n-halves; full-C 3x34 window staged
// once in swizzled LDS; 18 MFMA k-steps.
// Main (R19): wave (ntm=wv&1, toh=wv>>1); lane (n16,q4) gathers 4 corners of
// pixel ntm*16+n16 at channels g*32+q4*8, lerps in regs -> b-frag -> MFMA
// with a-frags for to=2toh,2toh+1.  No LDS, no barriers in this loop.
// mfma_f32_16x16x32_bf16 layouts (m89/m120 verified):
//   A: lane holds A[m=lane&15][k=(lane>>4)*8+j]
//   B: lane holds B[k=(lane>>4)*8+j][n=lane&15]
//   D: reg r holds D[m=(lane>>4)*4+r][n=lane&15]
// ---------------------------------------------------------------------------
__global__ __launch_bounds__(256, 8) void fused_deform(
    const bf16* __restrict__ xT, const bf16* __restrict__ wfC,
    const bf16* __restrict__ wfM, const float* __restrict__ b_off,
    const float* __restrict__ b_mask, float* __restrict__ out) {
  __shared__ __align__(16) char smem[SMEM_BYTES];
  bf16* stage = (bf16*)smem;              // 102 rows swz = 13,056 (conv)
  float* bufF = (float*)smem;             // [32][55] fp32 = 7,040 (conv out)
  float* valF = (float*)smem;             // [64][36] fp32 = 9,216 (out xpose)
  unsigned int* buf2a = (unsigned int*)(smem + B2A_OFF);  // w00|w01 f16x2
  unsigned int* buf2b = (unsigned int*)(smem + B2B_OFF);  // w10|w11 f16x2
  unsigned int* buf2c = (unsigned int*)(smem + B2C_OFF);  // y0|x0|y1|x1 u8x4

  const int tid = threadIdx.x;
  const int lane = tid & 63;
  const int wv = tid >> 6;        // 0..3
  const int n16 = lane & 15;
  const int q4 = lane >> 4;
  const int to = wv;              // conv: this wave's out-channel 16-tile

  // XCD-aware swizzle: XCD (blockIdx%8) works one image (2 MB bf16 in L2).
  const int g8 = blockIdx.x & 7;
  const int slot = blockIdx.x >> 3;      // 0..255
  const int b = g8 >> 1;
  const int ti = (g8 & 1) * 256 + slot;  // 0..511: 32-px tile index
  const int h0 = ti >> 2;
  const int w0 = (ti & 3) * 32;
  const bf16* xb = xT + (size_t)b * HW * C;

  bf16x8 zero8;
#pragma unroll
  for (int j = 0; j < 8; ++j) zero8[j] = (bf16)0.f;

  // ============ conv: stage full-C window once, 18 MFMA k-steps ============
#pragma unroll
  for (int it = 0; it < 4; ++it) {  // 816 = 3 rows x 34 px x 8 chunks
    int id = it * 256 + tid;
    if (id < 816) {
      int chk = id & 7;
      int rest = id >> 3;
      int wp = rest % 34;
      int r = rest / 34;
      int yy = h0 + r - 1;
      int xx = w0 + wp - 1;
      bf16x8 v = zero8;
      if ((unsigned)yy < (unsigned)H && (unsigned)xx < (unsigned)W)
        v = *(const bf16x8*)(xb + (size_t)((yy << 7) + xx) * C + chk * 8);
      *(bf16x8*)(stage + soff(r * 34 + wp, chk)) = v;
    }
  }
  __syncthreads();
  f32x4 accC[2] = {{0.f,0.f,0.f,0.f},{0.f,0.f,0.f,0.f}};
#pragma unroll 1
  for (int ph = 0; ph < 2; ++ph) {
#pragma unroll
    for (int kk = 0; kk < 9; ++kk) {
      // one a-frag load, used for both n-halves
      bf16x8 afr = *(const bf16x8*)(wfC +
          (size_t)(((ph * 9 + kk) * 4 + to) * 64 + lane) * 8);
#pragma unroll
      for (int nt = 0; nt < 2; ++nt) {
        int row = (kk / 3) * 34 + nt * 16 + n16 + kk % 3;
        bf16x8 bfr = *(const bf16x8*)(stage + soff(row, ph * 4 + q4));
        accC[nt] = __builtin_amdgcn_mfma_f32_16x16x32_bf16(afr, bfr, accC[nt], 0, 0, 0);
      }
    }
  }
  __syncthreads();  // stage readers done before bufF overwrites

  // conv epilogue: bias + sigmoid -> bufF[p][o]
#pragma unroll
  for (int nt = 0; nt < 2; ++nt)
#pragma unroll
    for (int r = 0; r < 4; ++r) {
      int o = to * 16 + q4 * 4 + r;
      int p = nt * 16 + n16;
      float a = accC[nt][r];
      if (o < NOFF) {
        bufF[p * BSTR + o] = a + b_off[o];
      } else if (o < 54) {
        float s = a + b_mask[o - NOFF];
        bufF[p * BSTR + o] = 1.f / (1.f + __expf(-s));
      }
    }
  __syncthreads();

  // ----- bilinear precompute: 576 (p,gk) tasks -> packed 12B params -----
  // bufF [0,7040) and buf2 [13056,19968) disjoint: direct write, 1 barrier.
#pragma unroll
  for (int it = 0; it < 3; ++it) {
    int t = it * 256 + tid;
    if (t < 576) {
      int p = t & 31;
      int gk = t >> 5;
      int tap = gk % 9;
      float offy = bufF[p * BSTR + 2 * gk];
      float offx = bufF[p * BSTR + 2 * gk + 1];
      float m = bufF[p * BSTR + NOFF + gk];
      float py = offy + (float)(h0 + tap / 3 - 1);
      float px = offx + (float)(w0 + p + tap % 3 - 1);
      float y0f = floorf(py), x0f = floorf(px);
      float wy1 = py - y0f, wx1 = px - x0f;
      float wy0 = 1.f - wy1, wx0 = 1.f - wx1;
      int y0 = (int)y0f, x0 = (int)x0f;
      int y1 = y0 + 1, x1 = x0 + 1;
      bool y0ok = (unsigned)y0 < (unsigned)H, y1ok = (unsigned)y1 < (unsigned)H;
      bool x0ok = (unsigned)x0 < (unsigned)W, x1ok = (unsigned)x1 < (unsigned)W;
      float w00 = (y0ok && x0ok) ? wy0 * wx0 * m : 0.f;
      float w01 = (y0ok && x1ok) ? wy0 * wx1 * m : 0.f;
      float w10 = (y1ok && x0ok) ? wy1 * wx0 * m : 0.f;
      float w11 = (y1ok && x1ok) ? wy1 * wx1 * m : 0.f;
      unsigned int y0c = (unsigned)min(max(y0, 0), H - 1);
      unsigned int y1c = (unsigned)min(max(y1, 0), H - 1);
      unsigned int x0c = (unsigned)min(max(x0, 0), W - 1);
      unsigned int x1c = (unsigned)min(max(x1, 0), W - 1);
      int idx = p * 18 + gk;
      buf2a[idx] = (unsigned)f2h_bits(w00) | ((unsigned)f2h_bits(w01) << 16);
      buf2b[idx] = (unsigned)f2h_bits(w10) | ((unsigned)f2h_bits(w11) << 16);
      buf2c[idx] = y0c | (x0c << 8) | (y1c << 16) | (x1c << 24);
    }
  }
  __syncthreads();

  // ------- main deform: in-register b-frag, no LDS staging, no barriers ----
  f32x4 accM[2] = {{0.f,0.f,0.f,0.f},{0.f,0.f,0.f,0.f}};
  const int ntm = wv & 1;         // main-phase pixel half
  const int toh = wv >> 1;        // main-phase to-pair {2toh, 2toh+1}
  const int px = ntm * 16 + n16;  // this lane's pixel
  const bf16* g0p = xb + q4 * 8;        // g=0 channel slice base
  const bf16* g1p = xb + 32 + q4 * 8;   // g=1 channel slice base
#pragma unroll 1
  for (int tap = 0; tap < 9; ++tap) {
    int i0 = px * 18 + tap;          // g=0 params
    int i1 = i0 + 9;                 // g=1 params
    unsigned wA0 = buf2a[i0], wB0 = buf2b[i0], co0 = buf2c[i0];
    unsigned wA1 = buf2a[i1], wB1 = buf2b[i1], co1 = buf2c[i1];
    int ry0 = (int)(co0 & 255) << 7, rx0 = (int)((co0 >> 8) & 255);
    int ry1 = (int)((co0 >> 16) & 255) << 7, rx1 = (int)(co0 >> 24);
    int sy0 = (int)(co1 & 255) << 7, sx0 = (int)((co1 >> 8) & 255);
    int sy1 = (int)((co1 >> 16) & 255) << 7, sx1 = (int)(co1 >> 24);
    // issue all 8 corner loads (4 per group) before consuming
    bf16x8 u00 = *(const bf16x8*)(g0p + (size_t)(ry0 + rx0) * C);
    bf16x8 u01 = *(const bf16x8*)(g0p + (size_t)(ry0 + rx1) * C);
    bf16x8 u10 = *(const bf16x8*)(g0p + (size_t)(ry1 + rx0) * C);
    bf16x8 u11 = *(const bf16x8*)(g0p + (size_t)(ry1 + rx1) * C);
    bf16x8 s00 = *(const bf16x8*)(g1p + (size_t)(sy0 + sx0) * C);
    bf16x8 s01 = *(const bf16x8*)(g1p + (size_t)(sy0 + sx1) * C);
    bf16x8 s10 = *(const bf16x8*)(g1p + (size_t)(sy1 + sx0) * C);
    bf16x8 s11 = *(const bf16x8*)(g1p + (size_t)(sy1 + sx1) * C);
    // g=0 lerp -> b-frag -> 2 MFMA
    {
      float w00 = h2f(wA0 & 0xffff), w01 = h2f(wA0 >> 16);
      float w10 = h2f(wB0 & 0xffff), w11 = h2f(wB0 >> 16);
      bf16x8 bfr;
#pragma unroll
      for (int j = 0; j < 8; ++j) {
        float v = (float)u00[j] * w00 + (float)u01[j] * w01 +
                  (float)u10[j] * w10 + (float)u11[j] * w11;
        bfr[j] = (bf16)v;
      }
#pragma unroll
      for (int i = 0; i < 2; ++i) {
        bf16x8 afr = *(const bf16x8*)(wfM +
            (size_t)((tap * 4 + 2 * toh + i) * 64 + lane) * 8);
        accM[i] = __builtin_amdgcn_mfma_f32_16x16x32_bf16(afr, bfr, accM[i], 0, 0, 0);
      }
    }
    // g=1 lerp -> b-frag -> 2 MFMA
    {
      float w00 = h2f(wA1 & 0xffff), w01 = h2f(wA1 >> 16);
      float w10 = h2f(wB1 & 0xffff), w11 = h2f(wB1 >> 16);
      bf16x8 bfr;
#pragma unroll
      for (int j = 0; j < 8; ++j) {
        float v = (float)s00[j] * w00 + (float)s01[j] * w01 +
                  (float)s10[j] * w10 + (float)s11[j] * w11;
        bfr[j] = (bf16)v;
      }
#pragma unroll
      for (int i = 0; i < 2; ++i) {
        bf16x8 afr = *(const bf16x8*)(wfM + (size_t)WFRAG +
            (size_t)((tap * 4 + 2 * toh + i) * 64 + lane) * 8);
        accM[i] = __builtin_amdgcn_mfma_f32_16x16x32_bf16(afr, bfr, accM[i], 0, 0, 0);
      }
    }
  }

  // -------- epilogue: LDS transpose -> coalesced NCHW dwordx4 stores -------
  // valF [0,9216) disjoint from buf2 [13056,...): safe to write immediately.
#pragma unroll
  for (int i = 0; i < 2; ++i)
#pragma unroll
    for (int r = 0; r < 4; ++r)
      valF[((2 * toh + i) * 16 + q4 * 4 + r) * VSTR + ntm * 16 + n16] =
          accM[i][r];
  __syncthreads();
  {
    float* ob = out + (size_t)b * O * HW + (h0 << 7) + w0;
#pragma unroll
    for (int it = 0; it < 2; ++it) {
      int id = it * 256 + tid;
      int o = id >> 3, seg = id & 7;
      f32x4 v = *(f32x4*)&valF[o * VSTR + seg * 4];
      *(f32x4*)&ob[(size_t)o * HW + seg * 4] = v;
    }
  }
}

// ---------------------------------------------------------------------------
extern "C" void kernel_launch(void* const* d_in, const int* in_sizes, int n_in,
                              void* d_out, int out_size, void* d_ws,
                              size_t ws_size, hipStream_t stream) {
  const float* x = (const float*)d_in[0];
  const float* w_main = (const float*)d_in[1];
  const float* w_off = (const float*)d_in[2];
  const float* b_off = (const float*)d_in[3];
  const float* w_mask = (const float*)d_in[4];
  const float* b_mask = (const float*)d_in[5];
  float* out = (float*)d_out;

  unsigned short* xT16 = (unsigned short*)d_ws;     // 8,388,608 B
  bf16* wfC = (bf16*)(xT16 + (size_t)BB * HW * C);  // 73,728 B
  bf16* wfM = wfC + 36864;                          // 73,728 B

  prep_all<<<1024, 256, 0, stream>>>(x, w_main, w_off, w_mask, xT16, wfC, wfM);
  fused_deform<<<2048, 256, 0, stream>>>((const bf16*)xT16, wfC, wfM, b_off,
                                         b_mask, out);
}

// Round 8
// 115.374 us; speedup vs baseline: 1.3658x; 1.3658x over previous
//
#include <hip/hip_runtime.h>
#include <math.h>

#define BB 4
#define C 64
#define O 64
#define H 128
#define W 128
#define K2 9
#define HW (H*W)
#define NOFF 36

typedef __bf16 bf16;
typedef bf16 bf16x8 __attribute__((ext_vector_type(8)));
typedef float f32x4 __attribute__((ext_vector_type(4)));
typedef unsigned short u16x8 __attribute__((ext_vector_type(8)));
typedef unsigned int u32x4 __attribute__((ext_vector_type(4)));

#define BSTR 55          /* bufF row stride (fp32 conv outputs) */
#define VSTR 36          /* valF row stride (fp32) */
/* R20: R17 geometry (32-px / 256-thr / 4-wave, grid 2048, cooperative
 * gather) + chunk-level software pipeline pinned with sched_barrier(0):
 * per chunk kc: [issue chunk kc+1's 12 loads -> held regs] | pin |
 * [setprio(1) MFMA on val[cur] setprio(0)] | pin | [wait+lerp+write
 * val[nxt]] | barrier.  vmcnt retires in-order, so held-load latency
 * drains under the MFMA phase's own a-frag loads + ds_reads.
 * val double-buffered -> ONE barrier per chunk; lerp weights re-read
 * from LDS in region 3 (saves 6 held VGPRs; held state = 48 VGPR).
 * LDS overlay (31,488 B):
 *   [0 .. 12,288)  val0 (main dbuf A)       [12,288..24,576) val1 (B)
 *   [0 .. 13,056)  stage 102 rows swz (conv; dies at conv barrier)
 *   [0 ..  7,040)  bufF[32][55]f32    [0..9,216) valF (final epilogue)
 *   [24,576..31,488) buf2a/b/c u32[576] (params; precompute -> main, RO)
 * 5 blocks/CU x 4 waves = 20 waves/CU; launch_bounds(256,5) -> VGPR cap
 * ~102 so the 48 held regs cannot be starved out (R16/R18/R19 lesson). */
#define VAL1_OFF 12288
#define B2A_OFF 24576
#define B2B_OFF 26880
#define B2C_OFF 29184
#define SMEM_BYTES 31488
#define WFRAG 18432      /* bf16 per conv-half / group: 9*4*64*8 */
#define NW_TOTAL 73728

__device__ inline unsigned short f2h_bits(float f) {
  _Float16 h = (_Float16)f;
  return __builtin_bit_cast(unsigned short, h);
}
__device__ inline float h2f(unsigned short u) {
  return (float)__builtin_bit_cast(_Float16, u);
}
/* swizzled LDS offset in bf16 units: row*64 + (chunk^(row&7))*8 */
__device__ inline int soff(int row, int chunk) {
  return row * 64 + ((chunk ^ (row & 7)) * 8);
}

// ---------------------------------------------------------------------------
// K1 (validated R6-R17): NCHW fp32 -> NHWC bf16 transpose (1024 blocks) +
// weight swizzle to MFMA a-frag order (first 288 blocks).
//  frag[(ph*9+kk)*4+to][lane][j] = Wrow[m=to*16+(lane&15)][u=kk*32+(lane>>4)*8+j]
//  K order u = tap*32 + c'.  wfC: m<36 w_off, m<54 w_mask, else 0.
// ---------------------------------------------------------------------------
__global__ __launch_bounds__(256) void prep_all(
    const float* __restrict__ x, const float* __restrict__ w_main,
    const float* __restrict__ w_off, const float* __restrict__ w_mask,
    unsigned short* __restrict__ xT16, bf16* __restrict__ wfC,
    bf16* __restrict__ wfM) {
  __shared__ float tile[64][69];
  int tid = threadIdx.x;
  int b = blockIdx.x >> 8;
  int p0 = (blockIdx.x & 255) * 64;
#pragma unroll
  for (int it = 0; it < 4; ++it) {
    int c = it * 16 + (tid >> 4);
    int p4 = (tid & 15) * 4;
    *(f32x4*)&tile[c][p4] =
        *(const f32x4*)(x + (size_t)(b * C + c) * HW + p0 + p4);
  }
  __syncthreads();
#pragma unroll
  for (int it = 0; it < 2; ++it) {
    int t = it * 256 + tid;
    int p = t >> 3;
    int h8 = t & 7;
    u16x8 o;
#pragma unroll
    for (int j = 0; j < 8; ++j) {
      bf16 v = (bf16)tile[h8 * 8 + j][p];
      o[j] = __builtin_bit_cast(unsigned short, v);
    }
    *(u16x8*)&xT16[(size_t)(b * HW + p0 + p) * C + h8 * 8] = o;
  }
  int i = blockIdx.x * 256 + tid;
  if (i < NW_TOTAL) {
    int which = (i >= 36864);
    int ii = which ? i - 36864 : i;
    int j = ii & 7;
    int l = (ii >> 3) & 63;
    int rest = ii >> 9;
    int to = rest & 3;
    int kk = (rest >> 2) % 9;
    int ph = (rest >> 2) / 9;
    int m = to * 16 + (l & 15);
    int u = kk * 32 + (l >> 4) * 8 + j;
    int tap = u >> 5;
    int c1 = u & 31;
    if (!which) {
      int c = ph * 32 + c1;
      float v = (m < NOFF) ? w_off[(m * C + c) * K2 + tap]
                : (m < 54) ? w_mask[((m - NOFF) * C + c) * K2 + tap]
                           : 0.f;
      wfC[ii] = (bf16)v;
    } else {
      wfM[ii] = (bf16)w_main[(m * C + ph * 32 + c1) * K2 + tap];
    }
  }
}

// ---------------------------------------------------------------------------
// K2: fused deform, 32-px tiles x 256 threads (4 waves), grid 2048.
// Conv (R17): wave wv=to, both n-halves; full-C 3x34 window staged once in
// swizzled LDS; 18 MFMA k-steps.  Main (R20): pipelined chunks, see header.
// mfma_f32_16x16x32_bf16 layouts (m89/m120 verified):
//   A: lane holds A[m=lane&15][k=(lane>>4)*8+j]
//   B: lane holds B[k=(lane>>4)*8+j][n=lane&15]
//   D: reg r holds D[m=(lane>>4)*4+r][n=lane&15]
// ---------------------------------------------------------------------------
__global__ __launch_bounds__(256, 5) void fused_deform(
    const bf16* __restrict__ xT, const bf16* __restrict__ wfC,
    const bf16* __restrict__ wfM, const float* __restrict__ b_off,
    const float* __restrict__ b_mask, float* __restrict__ out) {
  __shared__ __align__(16) char smem[SMEM_BYTES];
  bf16* stage = (bf16*)smem;              // 102 rows swz = 13,056 (conv)
  float* bufF = (float*)smem;             // [32][55] fp32 = 7,040 (conv out)
  float* valF = (float*)smem;             // [64][36] fp32 = 9,216 (out xpose)
  bf16* val0 = (bf16*)smem;               // [3][32][64] swz = 12,288
  bf16* val1 = (bf16*)(smem + VAL1_OFF);  // [3][32][64] swz = 12,288
  unsigned int* buf2a = (unsigned int*)(smem + B2A_OFF);  // w00|w01 f16x2
  unsigned int* buf2b = (unsigned int*)(smem + B2B_OFF);  // w10|w11 f16x2
  unsigned int* buf2c = (unsigned int*)(smem + B2C_OFF);  // y0|x0|y1|x1 u8x4

  const int tid = threadIdx.x;
  const int lane = tid & 63;
  const int wv = tid >> 6;        // 0..3
  const int n16 = lane & 15;
  const int q4 = lane >> 4;
  const int to = wv;              // this wave's out-channel 16-tile (0..3)
  const int pg = tid >> 3;        // gather pixel 0..31
  const int ch = tid & 7;         // gather 8-ch chunk 0..7 (abs ch = ch*8)

  // XCD-aware swizzle: XCD (blockIdx%8) works one image (2 MB bf16 in L2).
  const int g8 = blockIdx.x & 7;
  const int slot = blockIdx.x >> 3;      // 0..255
  const int b = g8 >> 1;
  const int ti = (g8 & 1) * 256 + slot;  // 0..511: 32-px tile index
  const int h0 = ti >> 2;
  const int w0 = (ti & 3) * 32;
  const bf16* xb = xT + (size_t)b * HW * C;

  bf16x8 zero8;
#pragma unroll
  for (int j = 0; j < 8; ++j) zero8[j] = (bf16)0.f;

  // ============ conv: stage full-C window once, 18 MFMA k-steps ============
#pragma unroll
  for (int it = 0; it < 4; ++it) {  // 816 = 3 rows x 34 px x 8 chunks
    int id = it * 256 + tid;
    if (id < 816) {
      int chk = id & 7;
      int rest = id >> 3;
      int wp = rest % 34;
      int r = rest / 34;
      int yy = h0 + r - 1;
      int xx = w0 + wp - 1;
      bf16x8 v = zero8;
      if ((unsigned)yy < (unsigned)H && (unsigned)xx < (unsigned)W)
        v = *(const bf16x8*)(xb + (size_t)((yy << 7) + xx) * C + chk * 8);
      *(bf16x8*)(stage + soff(r * 34 + wp, chk)) = v;
    }
  }
  __syncthreads();
  f32x4 accC[2] = {{0.f,0.f,0.f,0.f},{0.f,0.f,0.f,0.f}};
#pragma unroll 1
  for (int ph = 0; ph < 2; ++ph) {
#pragma unroll
    for (int kk = 0; kk < 9; ++kk) {
      // one a-frag load, used for both n-halves
      bf16x8 afr = *(const bf16x8*)(wfC +
          (size_t)(((ph * 9 + kk) * 4 + to) * 64 + lane) * 8);
#pragma unroll
      for (int nt = 0; nt < 2; ++nt) {
        int row = (kk / 3) * 34 + nt * 16 + n16 + kk % 3;
        bf16x8 bfr = *(const bf16x8*)(stage + soff(row, ph * 4 + q4));
        accC[nt] = __builtin_amdgcn_mfma_f32_16x16x32_bf16(afr, bfr, accC[nt], 0, 0, 0);
      }
    }
  }
  __syncthreads();  // stage readers done before bufF overwrites

  // conv epilogue: bias + sigmoid -> bufF[p][o]
#pragma unroll
  for (int nt = 0; nt < 2; ++nt)
#pragma unroll
    for (int r = 0; r < 4; ++r) {
      int o = to * 16 + q4 * 4 + r;
      int p = nt * 16 + n16;
      float a = accC[nt][r];
      if (o < NOFF) {
        bufF[p * BSTR + o] = a + b_off[o];
      } else if (o < 54) {
        float s = a + b_mask[o - NOFF];
        bufF[p * BSTR + o] = 1.f / (1.f + __expf(-s));
      }
    }
  __syncthreads();

  // ----- bilinear precompute: 576 (p,gk) tasks -> packed 12B params -----
  // bufF [0,7040) and buf2 [24576,31488) disjoint: direct write, 1 barrier.
#pragma unroll
  for (int it = 0; it < 3; ++it) {
    int t = it * 256 + tid;
    if (t < 576) {
      int p = t & 31;
      int gk = t >> 5;
      int tap = gk % 9;
      float offy = bufF[p * BSTR + 2 * gk];
      float offx = bufF[p * BSTR + 2 * gk + 1];
      float m = bufF[p * BSTR + NOFF + gk];
      float py = offy + (float)(h0 + tap / 3 - 1);
      float px = offx + (float)(w0 + p + tap % 3 - 1);
      float y0f = floorf(py), x0f = floorf(px);
      float wy1 = py - y0f, wx1 = px - x0f;
      float wy0 = 1.f - wy1, wx0 = 1.f - wx1;
      int y0 = (int)y0f, x0 = (int)x0f;
      int y1 = y0 + 1, x1 = x0 + 1;
      bool y0ok = (unsigned)y0 < (unsigned)H, y1ok = (unsigned)y1 < (unsigned)H;
      bool x0ok = (unsigned)x0 < (unsigned)W, x1ok = (unsigned)x1 < (unsigned)W;
      float w00 = (y0ok && x0ok) ? wy0 * wx0 * m : 0.f;
      float w01 = (y0ok && x1ok) ? wy0 * wx1 * m : 0.f;
      float w10 = (y1ok && x0ok) ? wy1 * wx0 * m : 0.f;
      float w11 = (y1ok && x1ok) ? wy1 * wx1 * m : 0.f;
      unsigned int y0c = (unsigned)min(max(y0, 0), H - 1);
      unsigned int y1c = (unsigned)min(max(y1, 0), H - 1);
      unsigned int x0c = (unsigned)min(max(x0, 0), W - 1);
      unsigned int x1c = (unsigned)min(max(x1, 0), W - 1);
      int idx = p * 18 + gk;
      buf2a[idx] = (unsigned)f2h_bits(w00) | ((unsigned)f2h_bits(w01) << 16);
      buf2b[idx] = (unsigned)f2h_bits(w10) | ((unsigned)f2h_bits(w11) << 16);
      buf2c[idx] = y0c | (x0c << 8) | (y1c << 16) | (x1c << 24);
    }
  }
  __syncthreads();

  // ---- main deform: pipelined chunks (issue-early, pinned), dbuf val ----
  f32x4 accM[2] = {{0.f,0.f,0.f,0.f},{0.f,0.f,0.f,0.f}};
  const bf16* bb = xb + ch * 8;   // this thread's 8-channel slice (abs)
  const int gg = ch >> 2;          // group of this chunk

  // prologue: gather chunk 0 -> val0 (exposed once)
#pragma unroll
  for (int t = 0; t < 3; ++t) {
    int idx = pg * 18 + gg * 9 + t;
    unsigned wA = buf2a[idx], wB = buf2b[idx], co = buf2c[idx];
    float w00 = h2f(wA & 0xffff), w01 = h2f(wA >> 16);
    float w10 = h2f(wB & 0xffff), w11 = h2f(wB >> 16);
    int r0 = (int)(co & 255) << 7;
    int x0 = (int)((co >> 8) & 255);
    int r1 = (int)((co >> 16) & 255) << 7;
    int x1 = (int)(co >> 24);
    bf16x8 v00 = *(const bf16x8*)(bb + (size_t)(r0 + x0) * C);
    bf16x8 v01 = *(const bf16x8*)(bb + (size_t)(r0 + x1) * C);
    bf16x8 v10 = *(const bf16x8*)(bb + (size_t)(r1 + x0) * C);
    bf16x8 v11 = *(const bf16x8*)(bb + (size_t)(r1 + x1) * C);
    bf16x8 res;
#pragma unroll
    for (int j = 0; j < 8; ++j) {
      float v = (float)v00[j] * w00 + (float)v01[j] * w01 +
                (float)v10[j] * w10 + (float)v11[j] * w11;
      res[j] = (bf16)v;
    }
    *(bf16x8*)(val0 + soff(t * 32 + pg, ch)) = res;
  }
  __syncthreads();

#pragma unroll 1
  for (int kc = 0; kc < 3; ++kc) {
    const bf16* cur = (kc & 1) ? val1 : val0;
    bf16* nxt = (kc & 1) ? val0 : val1;
    // (1) ISSUE next chunk's 12 cooperative loads into held regs
    bf16x8 hv[3][4];
    if (kc < 2) {
#pragma unroll
      for (int t = 0; t < 3; ++t) {
        unsigned co = buf2c[pg * 18 + gg * 9 + (kc + 1) * 3 + t];
        int r0 = (int)(co & 255) << 7;
        int x0 = (int)((co >> 8) & 255);
        int r1 = (int)((co >> 16) & 255) << 7;
        int x1 = (int)(co >> 24);
        hv[t][0] = *(const bf16x8*)(bb + (size_t)(r0 + x0) * C);
        hv[t][1] = *(const bf16x8*)(bb + (size_t)(r0 + x1) * C);
        hv[t][2] = *(const bf16x8*)(bb + (size_t)(r1 + x0) * C);
        hv[t][3] = *(const bf16x8*)(bb + (size_t)(r1 + x1) * C);
      }
    }
    __builtin_amdgcn_sched_barrier(0);  // pin: loads stay above MFMA phase
    // (2) MFMA phase for chunk kc from cur
    __builtin_amdgcn_s_setprio(1);
#pragma unroll
    for (int t = 0; t < 3; ++t) {
      int tap = kc * 3 + t;
#pragma unroll
      for (int g = 0; g < 2; ++g) {
        bf16x8 afr = *(const bf16x8*)(wfM + (size_t)g * WFRAG +
            (size_t)((tap * 4 + to) * 64 + lane) * 8);
#pragma unroll
        for (int nt = 0; nt < 2; ++nt) {
          int row = t * 32 + nt * 16 + n16;
          bf16x8 bfr = *(const bf16x8*)(cur + soff(row, g * 4 + q4));
          accM[nt] = __builtin_amdgcn_mfma_f32_16x16x32_bf16(afr, bfr, accM[nt], 0, 0, 0);
        }
      }
    }
    __builtin_amdgcn_s_setprio(0);
    __builtin_amdgcn_sched_barrier(0);  // pin: lerp/writes stay below
    // (3) lerp held lines -> nxt (weights re-read from LDS: saves 6 regs)
    if (kc < 2) {
#pragma unroll
      for (int t = 0; t < 3; ++t) {
        int idx = pg * 18 + gg * 9 + (kc + 1) * 3 + t;
        unsigned wA = buf2a[idx], wB = buf2b[idx];
        float w00 = h2f(wA & 0xffff), w01 = h2f(wA >> 16);
        float w10 = h2f(wB & 0xffff), w11 = h2f(wB >> 16);
        bf16x8 res;
#pragma unroll
        for (int j = 0; j < 8; ++j) {
          float v = (float)hv[t][0][j] * w00 + (float)hv[t][1][j] * w01 +
                    (float)hv[t][2][j] * w10 + (float)hv[t][3][j] * w11;
          res[j] = (bf16)v;
        }
        *(bf16x8*)(nxt + soff(t * 32 + pg, ch)) = res;
      }
    }
    __syncthreads();
  }

  // -------- epilogue: LDS transpose -> coalesced NCHW dwordx4 stores -------
  // final loop barrier ordered last MFMA reads before valF overwrites val0
#pragma unroll
  for (int nt = 0; nt < 2; ++nt)
#pragma unroll
    for (int r = 0; r < 4; ++r)
      valF[(to * 16 + q4 * 4 + r) * VSTR + nt * 16 + n16] = accM[nt][r];
  __syncthreads();
  {
    float* ob = out + (size_t)b * O * HW + (h0 << 7) + w0;
#pragma unroll
    for (int it = 0; it < 2; ++it) {
      int id = it * 256 + tid;
      int o = id >> 3, seg = id & 7;
      f32x4 v = *(f32x4*)&valF[o * VSTR + seg * 4];
      *(f32x4*)&ob[(size_t)o * HW + seg * 4] = v;
    }
  }
}

// ---------------------------------------------------------------------------
extern "C" void kernel_launch(void* const* d_in, const int* in_sizes, int n_in,
                              void* d_out, int out_size, void* d_ws,
                              size_t ws_size, hipStream_t stream) {
  const float* x = (const float*)d_in[0];
  const float* w_main = (const float*)d_in[1];
  const float* w_off = (const float*)d_in[2];
  const float* b_off = (const float*)d_in[3];
  const float* w_mask = (const float*)d_in[4];
  const float* b_mask = (const float*)d_in[5];
  float* out = (float*)d_out;

  unsigned short* xT16 = (unsigned short*)d_ws;     // 8,388,608 B
  bf16* wfC = (bf16*)(xT16 + (size_t)BB * HW * C);  // 73,728 B
  bf16* wfM = wfC + 36864;                          // 73,728 B

  prep_all<<<1024, 256, 0, stream>>>(x, w_main, w_off, w_mask, xT16, wfC, wfM);
  fused_deform<<<2048, 256, 0, stream>>>((const bf16*)xT16, wfC, wfM, b_off,
                                         b_mask, out);
}

// Round 9
// 110.537 us; speedup vs baseline: 1.4256x; 1.0438x over previous
//
#include <hip/hip_runtime.h>
#include <math.h>

#define BB 4
#define C 64
#define O 64
#define H 128
#define W 128
#define K2 9
#define HW (H*W)
#define NOFF 36

typedef __bf16 bf16;
typedef bf16 bf16x8 __attribute__((ext_vector_type(8)));
typedef float f32x4 __attribute__((ext_vector_type(4)));
typedef unsigned short u16x8 __attribute__((ext_vector_type(8)));
typedef unsigned int u32x4 __attribute__((ext_vector_type(4)));

#define BSTR 55          /* bufF row stride (fp32 conv outputs) */
#define VSTR 36          /* valF row stride (fp32) */
/* R21: R17 geometry + WAVE SPECIALIZATION in the main loop (zero occupancy
 * cost, unlike R16/R20's pipelines).  After precompute: waves 0-1 = producers
 * (16 px each, all 9 taps: 8 corner loads + 2 lerps + 2 ds_writes per tap),
 * waves 2-3 = consumers (32 out-ch each: 4 ds_read b-frags + 8 MFMA per tap).
 * val = 3-slot ring (4,096 B per tap slot); flags: produced[18], consumed[18]
 * (2 halves per tap).  Producers recycle slot t-3 after both consumers sign.
 * Gather L2 latency hides under other waves' MFMA/lerp continuously instead
 * of being barrier-exposed 3x per block (R17 had 5 main-loop barriers; now 0).
 * LDS overlay (19,456 B):
 *   [0 .. 12,288)  val ring 3 x [32][64] swz   (main loop)
 *   [0 .. 13,056)  stage 102 rows swz (conv; dies at conv barrier)
 *   [0 ..  7,040)  bufF[32][55]f32 (conv out; dies in precompute)
 *   [0 ..  9,216)  valF[64][36]f32 (epilogue, after ring fully consumed)
 *   [12,288..19,200) buf2a/b/c u32[576] (params; precompute -> main, RO)
 *   [19,200..19,344) flags u32[36]
 * 8 x 19,456 = 155,648 <= 160 KiB -> 8 blocks/CU = 32 waves/CU (HW max).
 * launch_bounds(256,8): VGPR cap 64 (R17 measured 60-class usage). */
#define VAL_SLOT 2048    /* bf16 units per ring slot: 32 rows x 64 */
#define B2A_OFF 12288
#define B2B_OFF 14592
#define B2C_OFF 16896
#define FLG_OFF 19200
#define SMEM_BYTES 19456
#define WFRAG 18432      /* bf16 per conv-half / group: 9*4*64*8 */
#define NW_TOTAL 73728

__device__ inline unsigned short f2h_bits(float f) {
  _Float16 h = (_Float16)f;
  return __builtin_bit_cast(unsigned short, h);
}
__device__ inline float h2f(unsigned short u) {
  return (float)__builtin_bit_cast(_Float16, u);
}
/* swizzled LDS offset in bf16 units: row*64 + (chunk^(row&7))*8 */
__device__ inline int soff(int row, int chunk) {
  return row * 64 + ((chunk ^ (row & 7)) * 8);
}

// ---------------------------------------------------------------------------
// K1 (validated R6-R17): NCHW fp32 -> NHWC bf16 transpose (1024 blocks) +
// weight swizzle to MFMA a-frag order (first 288 blocks).
//  frag[(ph*9+kk)*4+to][lane][j] = Wrow[m=to*16+(lane&15)][u=kk*32+(lane>>4)*8+j]
//  K order u = tap*32 + c'.  wfC: m<36 w_off, m<54 w_mask, else 0.
// ---------------------------------------------------------------------------
__global__ __launch_bounds__(256) void prep_all(
    const float* __restrict__ x, const float* __restrict__ w_main,
    const float* __restrict__ w_off, const float* __restrict__ w_mask,
    unsigned short* __restrict__ xT16, bf16* __restrict__ wfC,
    bf16* __restrict__ wfM) {
  __shared__ float tile[64][69];
  int tid = threadIdx.x;
  int b = blockIdx.x >> 8;
  int p0 = (blockIdx.x & 255) * 64;
#pragma unroll
  for (int it = 0; it < 4; ++it) {
    int c = it * 16 + (tid >> 4);
    int p4 = (tid & 15) * 4;
    *(f32x4*)&tile[c][p4] =
        *(const f32x4*)(x + (size_t)(b * C + c) * HW + p0 + p4);
  }
  __syncthreads();
#pragma unroll
  for (int it = 0; it < 2; ++it) {
    int t = it * 256 + tid;
    int p = t >> 3;
    int h8 = t & 7;
    u16x8 o;
#pragma unroll
    for (int j = 0; j < 8; ++j) {
      bf16 v = (bf16)tile[h8 * 8 + j][p];
      o[j] = __builtin_bit_cast(unsigned short, v);
    }
    *(u16x8*)&xT16[(size_t)(b * HW + p0 + p) * C + h8 * 8] = o;
  }
  int i = blockIdx.x * 256 + tid;
  if (i < NW_TOTAL) {
    int which = (i >= 36864);
    int ii = which ? i - 36864 : i;
    int j = ii & 7;
    int l = (ii >> 3) & 63;
    int rest = ii >> 9;
    int to = rest & 3;
    int kk = (rest >> 2) % 9;
    int ph = (rest >> 2) / 9;
    int m = to * 16 + (l & 15);
    int u = kk * 32 + (l >> 4) * 8 + j;
    int tap = u >> 5;
    int c1 = u & 31;
    if (!which) {
      int c = ph * 32 + c1;
      float v = (m < NOFF) ? w_off[(m * C + c) * K2 + tap]
                : (m < 54) ? w_mask[((m - NOFF) * C + c) * K2 + tap]
                           : 0.f;
      wfC[ii] = (bf16)v;
    } else {
      wfM[ii] = (bf16)w_main[(m * C + ph * 32 + c1) * K2 + tap];
    }
  }
}

// ---------------------------------------------------------------------------
// K2: fused deform, 32-px tiles x 256 threads (4 waves), grid 2048.
// Conv (R17): wave wv=to, both n-halves; full-C 3x34 window staged once in
// swizzled LDS; 18 MFMA k-steps.  Main (R21): producer/consumer waves over a
// 3-slot val ring with LDS flags -- see file header.
// mfma_f32_16x16x32_bf16 layouts (m89/m120 verified):
//   A: lane holds A[m=lane&15][k=(lane>>4)*8+j]
//   B: lane holds B[k=(lane>>4)*8+j][n=lane&15]
//   D: reg r holds D[m=(lane>>4)*4+r][n=lane&15]
// ---------------------------------------------------------------------------
__global__ __launch_bounds__(256, 8) void fused_deform(
    const bf16* __restrict__ xT, const bf16* __restrict__ wfC,
    const bf16* __restrict__ wfM, const float* __restrict__ b_off,
    const float* __restrict__ b_mask, float* __restrict__ out) {
  __shared__ __align__(16) char smem[SMEM_BYTES];
  bf16* stage = (bf16*)smem;              // 102 rows swz = 13,056 (conv)
  float* bufF = (float*)smem;             // [32][55] fp32 = 7,040 (conv out)
  float* valF = (float*)smem;             // [64][36] fp32 = 9,216 (epilogue)
  bf16* val = (bf16*)smem;                // ring: 3 x [32][64] swz
  unsigned int* buf2a = (unsigned int*)(smem + B2A_OFF);  // w00|w01 f16x2
  unsigned int* buf2b = (unsigned int*)(smem + B2B_OFF);  // w10|w11 f16x2
  unsigned int* buf2c = (unsigned int*)(smem + B2C_OFF);  // y0|x0|y1|x1 u8x4
  volatile unsigned int* prod = (volatile unsigned int*)(smem + FLG_OFF);
  volatile unsigned int* cons = prod + 18;

  const int tid = threadIdx.x;
  const int lane = tid & 63;
  const int wv = tid >> 6;        // 0..3
  const int n16 = lane & 15;
  const int q4 = lane >> 4;
  const int to = wv;              // conv: this wave's out-channel 16-tile

  // XCD-aware swizzle: XCD (blockIdx%8) works one image (2 MB bf16 in L2).
  const int g8 = blockIdx.x & 7;
  const int slot0 = blockIdx.x >> 3;     // 0..255
  const int b = g8 >> 1;
  const int ti = (g8 & 1) * 256 + slot0; // 0..511: 32-px tile index
  const int h0 = ti >> 2;
  const int w0 = (ti & 3) * 32;
  const bf16* xb = xT + (size_t)b * HW * C;

  // flag init (region disjoint from stage; ordered by the stage barrier)
  if (tid < 36) prod[tid] = 0u;

  bf16x8 zero8;
#pragma unroll
  for (int j = 0; j < 8; ++j) zero8[j] = (bf16)0.f;

  // ============ conv: stage full-C window once, 18 MFMA k-steps ============
#pragma unroll
  for (int it = 0; it < 4; ++it) {  // 816 = 3 rows x 34 px x 8 chunks
    int id = it * 256 + tid;
    if (id < 816) {
      int chk = id & 7;
      int rest = id >> 3;
      int wp = rest % 34;
      int r = rest / 34;
      int yy = h0 + r - 1;
      int xx = w0 + wp - 1;
      bf16x8 v = zero8;
      if ((unsigned)yy < (unsigned)H && (unsigned)xx < (unsigned)W)
        v = *(const bf16x8*)(xb + (size_t)((yy << 7) + xx) * C + chk * 8);
      *(bf16x8*)(stage + soff(r * 34 + wp, chk)) = v;
    }
  }
  __syncthreads();
  f32x4 accC[2] = {{0.f,0.f,0.f,0.f},{0.f,0.f,0.f,0.f}};
#pragma unroll 1
  for (int ph = 0; ph < 2; ++ph) {
#pragma unroll
    for (int kk = 0; kk < 9; ++kk) {
      bf16x8 afr = *(const bf16x8*)(wfC +
          (size_t)(((ph * 9 + kk) * 4 + to) * 64 + lane) * 8);
#pragma unroll
      for (int nt = 0; nt < 2; ++nt) {
        int row = (kk / 3) * 34 + nt * 16 + n16 + kk % 3;
        bf16x8 bfr = *(const bf16x8*)(stage + soff(row, ph * 4 + q4));
        accC[nt] = __builtin_amdgcn_mfma_f32_16x16x32_bf16(afr, bfr, accC[nt], 0, 0, 0);
      }
    }
  }
  __syncthreads();  // stage readers done before bufF overwrites

  // conv epilogue: bias + sigmoid -> bufF[p][o]
#pragma unroll
  for (int nt = 0; nt < 2; ++nt)
#pragma unroll
    for (int r = 0; r < 4; ++r) {
      int o = to * 16 + q4 * 4 + r;
      int p = nt * 16 + n16;
      float a = accC[nt][r];
      if (o < NOFF) {
        bufF[p * BSTR + o] = a + b_off[o];
      } else if (o < 54) {
        float s = a + b_mask[o - NOFF];
        bufF[p * BSTR + o] = 1.f / (1.f + __expf(-s));
      }
    }
  __syncthreads();

  // ----- bilinear precompute: 576 (p,gk) tasks -> packed 12B params -----
#pragma unroll
  for (int it = 0; it < 3; ++it) {
    int t = it * 256 + tid;
    if (t < 576) {
      int p = t & 31;
      int gk = t >> 5;
      int tap = gk % 9;
      float offy = bufF[p * BSTR + 2 * gk];
      float offx = bufF[p * BSTR + 2 * gk + 1];
      float m = bufF[p * BSTR + NOFF + gk];
      float py = offy + (float)(h0 + tap / 3 - 1);
      float px = offx + (float)(w0 + p + tap % 3 - 1);
      float y0f = floorf(py), x0f = floorf(px);
      float wy1 = py - y0f, wx1 = px - x0f;
      float wy0 = 1.f - wy1, wx0 = 1.f - wx1;
      int y0 = (int)y0f, x0 = (int)x0f;
      int y1 = y0 + 1, x1 = x0 + 1;
      bool y0ok = (unsigned)y0 < (unsigned)H, y1ok = (unsigned)y1 < (unsigned)H;
      bool x0ok = (unsigned)x0 < (unsigned)W, x1ok = (unsigned)x1 < (unsigned)W;
      float w00 = (y0ok && x0ok) ? wy0 * wx0 * m : 0.f;
      float w01 = (y0ok && x1ok) ? wy0 * wx1 * m : 0.f;
      float w10 = (y1ok && x0ok) ? wy1 * wx0 * m : 0.f;
      float w11 = (y1ok && x1ok) ? wy1 * wx1 * m : 0.f;
      unsigned int y0c = (unsigned)min(max(y0, 0), H - 1);
      unsigned int y1c = (unsigned)min(max(y1, 0), H - 1);
      unsigned int x0c = (unsigned)min(max(x0, 0), W - 1);
      unsigned int x1c = (unsigned)min(max(x1, 0), W - 1);
      int idx = p * 18 + gk;
      buf2a[idx] = (unsigned)f2h_bits(w00) | ((unsigned)f2h_bits(w01) << 16);
      buf2b[idx] = (unsigned)f2h_bits(w10) | ((unsigned)f2h_bits(w11) << 16);
      buf2c[idx] = y0c | (x0c << 8) | (y1c << 16) | (x1c << 24);
    }
  }
  __syncthreads();  // params + zeroed flags visible to all waves

  // ========== main deform: producer/consumer over 3-slot val ring ==========
  if (wv < 2) {
    // ---- PRODUCER (waves 0-1): 16 px each, both groups, all 9 taps ----
    const int pgp = tid >> 2;       // pixel 0..31
    const int ch2 = tid & 3;        // g=0 chunk; g=1 chunk = ch2+4
    const bf16* bb0 = xb + ch2 * 8;
    const bf16* bb1 = xb + (ch2 + 4) * 8;
#pragma unroll 1
    for (int t = 0; t < 9; ++t) {
      if (t >= 3) {  // ring slot recycle: both consumers done with tap t-3
        while (cons[2 * (t - 3)] == 0u || cons[2 * (t - 3) + 1] == 0u)
          __builtin_amdgcn_s_sleep(1);
      }
      bf16* dst = val + (t % 3) * VAL_SLOT;
      int i0 = pgp * 18 + t;        // g=0 params
      int i1 = i0 + 9;              // g=1 params
      unsigned co0 = buf2c[i0], co1 = buf2c[i1];
      int r0 = (int)(co0 & 255) << 7, x0 = (int)((co0 >> 8) & 255);
      int r1 = (int)((co0 >> 16) & 255) << 7, x1 = (int)(co0 >> 24);
      int s0 = (int)(co1 & 255) << 7, z0 = (int)((co1 >> 8) & 255);
      int s1 = (int)((co1 >> 16) & 255) << 7, z1 = (int)(co1 >> 24);
      bf16x8 u00 = *(const bf16x8*)(bb0 + (size_t)(r0 + x0) * C);
      bf16x8 u01 = *(const bf16x8*)(bb0 + (size_t)(r0 + x1) * C);
      bf16x8 u10 = *(const bf16x8*)(bb0 + (size_t)(r1 + x0) * C);
      bf16x8 u11 = *(const bf16x8*)(bb0 + (size_t)(r1 + x1) * C);
      bf16x8 v00 = *(const bf16x8*)(bb1 + (size_t)(s0 + z0) * C);
      bf16x8 v01 = *(const bf16x8*)(bb1 + (size_t)(s0 + z1) * C);
      bf16x8 v10 = *(const bf16x8*)(bb1 + (size_t)(s1 + z0) * C);
      bf16x8 v11 = *(const bf16x8*)(bb1 + (size_t)(s1 + z1) * C);
      unsigned wA0 = buf2a[i0], wB0 = buf2b[i0];
      unsigned wA1 = buf2a[i1], wB1 = buf2b[i1];
      {
        float a0 = h2f(wA0 & 0xffff), a1 = h2f(wA0 >> 16);
        float a2 = h2f(wB0 & 0xffff), a3 = h2f(wB0 >> 16);
        bf16x8 res;
#pragma unroll
        for (int j = 0; j < 8; ++j) {
          float v = (float)u00[j] * a0 + (float)u01[j] * a1 +
                    (float)u10[j] * a2 + (float)u11[j] * a3;
          res[j] = (bf16)v;
        }
        *(bf16x8*)(dst + soff(pgp, ch2)) = res;
      }
      {
        float a0 = h2f(wA1 & 0xffff), a1 = h2f(wA1 >> 16);
        float a2 = h2f(wB1 & 0xffff), a3 = h2f(wB1 >> 16);
        bf16x8 res;
#pragma unroll
        for (int j = 0; j < 8; ++j) {
          float v = (float)v00[j] * a0 + (float)v01[j] * a1 +
                    (float)v10[j] * a2 + (float)v11[j] * a3;
          res[j] = (bf16)v;
        }
        *(bf16x8*)(dst + soff(pgp, ch2 + 4)) = res;
      }
      __threadfence_block();       // ds_writes visible before the flag
      if (lane == 0) prod[2 * t + wv] = 1u;
    }
  } else {
    // ---- CONSUMER (waves 2-3): 32 out-ch each, all pixels, all 9 taps ----
    const int wv2 = wv - 2;        // 0..1 -> to pair {2wv2, 2wv2+1}
    f32x4 acc[2][2] = {{{0.f,0.f,0.f,0.f},{0.f,0.f,0.f,0.f}},
                       {{0.f,0.f,0.f,0.f},{0.f,0.f,0.f,0.f}}};
#pragma unroll 1
    for (int t = 0; t < 9; ++t) {
      while (prod[2 * t] == 0u || prod[2 * t + 1] == 0u)
        __builtin_amdgcn_s_sleep(1);
      const bf16* src = val + (t % 3) * VAL_SLOT;
#pragma unroll
      for (int g = 0; g < 2; ++g) {
        bf16x8 bfr0 = *(const bf16x8*)(src + soff(n16, g * 4 + q4));
        bf16x8 bfr1 = *(const bf16x8*)(src + soff(16 + n16, g * 4 + q4));
#pragma unroll
        for (int i = 0; i < 2; ++i) {
          int tox = wv2 * 2 + i;
          bf16x8 afr = *(const bf16x8*)(wfM + (size_t)g * WFRAG +
              (size_t)((t * 4 + tox) * 64 + lane) * 8);
          acc[i][0] = __builtin_amdgcn_mfma_f32_16x16x32_bf16(afr, bfr0, acc[i][0], 0, 0, 0);
          acc[i][1] = __builtin_amdgcn_mfma_f32_16x16x32_bf16(afr, bfr1, acc[i][1], 0, 0, 0);
        }
      }
      __threadfence_block();       // ds_reads retired before the flag
      if (lane == 0) cons[2 * t + wv2] = 1u;
    }
    // both consumers done with the ring before valF overlays it
    while (cons[16] == 0u || cons[17] == 0u) __builtin_amdgcn_s_sleep(1);
#pragma unroll
    for (int i = 0; i < 2; ++i)
#pragma unroll
      for (int nt = 0; nt < 2; ++nt)
#pragma unroll
        for (int r = 0; r < 4; ++r)
          valF[((wv2 * 2 + i) * 16 + q4 * 4 + r) * VSTR + nt * 16 + n16] =
              acc[i][nt][r];
  }
  __syncthreads();

  // -------- epilogue: coalesced NCHW dwordx4 stores from valF --------
  {
    float* ob = out + (size_t)b * O * HW + (h0 << 7) + w0;
#pragma unroll
    for (int it = 0; it < 2; ++it) {
      int id = it * 256 + tid;
      int o = id >> 3, seg = id & 7;
      f32x4 v = *(f32x4*)&valF[o * VSTR + seg * 4];
      *(f32x4*)&ob[(size_t)o * HW + seg * 4] = v;
    }
  }
}

// ---------------------------------------------------------------------------
extern "C" void kernel_launch(void* const* d_in, const int* in_sizes, int n_in,
                              void* d_out, int out_size, void* d_ws,
                              size_t ws_size, hipStream_t stream) {
  const float* x = (const float*)d_in[0];
  const float* w_main = (const float*)d_in[1];
  const float* w_off = (const float*)d_in[2];
  const float* b_off = (const float*)d_in[3];
  const float* w_mask = (const float*)d_in[4];
  const float* b_mask = (const float*)d_in[5];
  float* out = (float*)d_out;

  unsigned short* xT16 = (unsigned short*)d_ws;     // 8,388,608 B
  bf16* wfC = (bf16*)(xT16 + (size_t)BB * HW * C);  // 73,728 B
  bf16* wfM = wfC + 36864;                          // 73,728 B

  prep_all<<<1024, 256, 0, stream>>>(x, w_main, w_off, w_mask, xT16, wfC, wfM);
  fused_deform<<<2048, 256, 0, stream>>>((const bf16*)xT16, wfC, wfM, b_off,
                                         b_mask, out);
}

// Round 10
// 105.544 us; speedup vs baseline: 1.4930x; 1.0473x over previous
//
#include <hip/hip_runtime.h>
#include <math.h>

#define BB 4
#define C 64
#define O 64
#define H 128
#define W 128
#define K2 9
#define HW (H*W)
#define NOFF 36

typedef __bf16 bf16;
typedef bf16 bf16x8 __attribute__((ext_vector_type(8)));
typedef float f32x4 __attribute__((ext_vector_type(4)));
typedef unsigned short u16x8 __attribute__((ext_vector_type(8)));
typedef unsigned int u32x4 __attribute__((ext_vector_type(4)));

#define BSTR 55          /* bufF row stride (fp32 conv outputs) */
#define VSTR 36          /* valF row stride (fp32) */
/* R22 = R17 (best measured: 105.15) + s_setprio(1) around MFMA clusters.
 * R17 LDS diet -> 8 blocks/CU (32 waves/CU = HW max).
 * stage/val: stride 64 bf16 (128B/px, NO pad) + XOR chunk swizzle
 *   off(row,chunk) = row*64 + ((chunk^(row&7))*8)   [bf16 units]
 * buf2: 12B/entry packed as 3 flat u32 arrays.
 * Overlay (19,200 B total):
 *   [0 .. 12,288)   val[3][32][64]   (main loop)
 *   [0 .. 13,056)   stage[3][34][64] (conv; dies at conv-MFMA barrier)
 *   [0 ..  7,040)   bufF[32][55]f32  (conv out; dies in precompute)
 *   [0 ..  9,216)   valF[64][36]f32  (final epilogue only)
 *   [12,288..19,200) buf2a/b/c u32[576] each (precompute -> main)
 * 8 x 19,200 = 153,600 <= 160 KiB.  launch_bounds(256,8): VGPR cap 64. */
#define VAL_BYTES 12288
#define B2A_OFF 12288
#define B2B_OFF 14592
#define B2C_OFF 16896
#define SMEM_BYTES 19200
#define WFRAG 18432      /* bf16 per conv-half / group: 9*4*64*8 */
#define NW_TOTAL 73728

__device__ inline unsigned short f2h_bits(float f) {
  _Float16 h = (_Float16)f;
  return __builtin_bit_cast(unsigned short, h);
}
__device__ inline float h2f(unsigned short u) {
  return (float)__builtin_bit_cast(_Float16, u);
}
/* swizzled LDS offset in bf16 units: row*64 + (chunk^(row&7))*8 */
__device__ inline int soff(int row, int chunk) {
  return row * 64 + ((chunk ^ (row & 7)) * 8);
}

// ---------------------------------------------------------------------------
// K1 (validated R6-R17): NCHW fp32 -> NHWC bf16 transpose (1024 blocks) +
// weight swizzle to MFMA a-frag order (first 288 blocks).
//  frag[(ph*9+kk)*4+to][lane][j] = Wrow[m=to*16+(lane&15)][u=kk*32+(lane>>4)*8+j]
//  K order u = tap*32 + c'.  wfC: m<36 w_off, m<54 w_mask, else 0.
// ---------------------------------------------------------------------------
__global__ __launch_bounds__(256) void prep_all(
    const float* __restrict__ x, const float* __restrict__ w_main,
    const float* __restrict__ w_off, const float* __restrict__ w_mask,
    unsigned short* __restrict__ xT16, bf16* __restrict__ wfC,
    bf16* __restrict__ wfM) {
  __shared__ float tile[64][69];
  int tid = threadIdx.x;
  int b = blockIdx.x >> 8;
  int p0 = (blockIdx.x & 255) * 64;
#pragma unroll
  for (int it = 0; it < 4; ++it) {
    int c = it * 16 + (tid >> 4);
    int p4 = (tid & 15) * 4;
    *(f32x4*)&tile[c][p4] =
        *(const f32x4*)(x + (size_t)(b * C + c) * HW + p0 + p4);
  }
  __syncthreads();
#pragma unroll
  for (int it = 0; it < 2; ++it) {
    int t = it * 256 + tid;
    int p = t >> 3;
    int h8 = t & 7;
    u16x8 o;
#pragma unroll
    for (int j = 0; j < 8; ++j) {
      bf16 v = (bf16)tile[h8 * 8 + j][p];
      o[j] = __builtin_bit_cast(unsigned short, v);
    }
    *(u16x8*)&xT16[(size_t)(b * HW + p0 + p) * C + h8 * 8] = o;
  }
  int i = blockIdx.x * 256 + tid;
  if (i < NW_TOTAL) {
    int which = (i >= 36864);
    int ii = which ? i - 36864 : i;
    int j = ii & 7;
    int l = (ii >> 3) & 63;
    int rest = ii >> 9;
    int to = rest & 3;
    int kk = (rest >> 2) % 9;
    int ph = (rest >> 2) / 9;
    int m = to * 16 + (l & 15);
    int u = kk * 32 + (l >> 4) * 8 + j;
    int tap = u >> 5;
    int c1 = u & 31;
    if (!which) {
      int c = ph * 32 + c1;
      float v = (m < NOFF) ? w_off[(m * C + c) * K2 + tap]
                : (m < 54) ? w_mask[((m - NOFF) * C + c) * K2 + tap]
                           : 0.f;
      wfC[ii] = (bf16)v;
    } else {
      wfM[ii] = (bf16)w_main[(m * C + ph * 32 + c1) * K2 + tap];
    }
  }
}

// ---------------------------------------------------------------------------
// K2: fused deform, 32-px tiles x 256 threads (4 waves), grid 2048.
// R13: one 'to' (16 out-ch) per wave across both n-halves.
// R17: LDS diet (19,200 B) -> 8 blocks/CU = 32 waves/CU (HW max).
// R22: + s_setprio(1) around the MFMA clusters (T5; only delta vs R17).
// Conv: full-C 3x34 window staged ONCE (swizzled stride-64 layout).
// Main: per 3-tap chunk each thread issues 12 independent corner loads,
// lerps, writes val; MFMA from val.
// mfma_f32_16x16x32_bf16 layouts (m89/m120 verified):
//   A: lane holds A[m=lane&15][k=(lane>>4)*8+j]
//   B: lane holds B[k=(lane>>4)*8+j][n=lane&15]
//   D: reg r holds D[m=(lane>>4)*4+r][n=lane&15]
// ---------------------------------------------------------------------------
__global__ __launch_bounds__(256, 8) void fused_deform(
    const bf16* __restrict__ xT, const bf16* __restrict__ wfC,
    const bf16* __restrict__ wfM, const float* __restrict__ b_off,
    const float* __restrict__ b_mask, float* __restrict__ out) {
  __shared__ __align__(16) char smem[SMEM_BYTES];
  bf16* stage = (bf16*)smem;              // [3][34][64] swz = 13,056 (conv)
  float* bufF = (float*)smem;             // [32][55] fp32 = 7,040 (conv out)
  float* valF = (float*)smem;             // [64][36] fp32 = 9,216 (out xpose)
  bf16* val = (bf16*)smem;                // [3][32][64] swz = 12,288 (main)
  unsigned int* buf2a = (unsigned int*)(smem + B2A_OFF);  // w00|w01 f16x2
  unsigned int* buf2b = (unsigned int*)(smem + B2B_OFF);  // w10|w11 f16x2
  unsigned int* buf2c = (unsigned int*)(smem + B2C_OFF);  // y0|x0|y1|x1 u8x4

  const int tid = threadIdx.x;
  const int lane = tid & 63;
  const int wv = tid >> 6;        // 0..3
  const int n16 = lane & 15;
  const int q4 = lane >> 4;
  const int to = wv;              // this wave's out-channel 16-tile (0..3)
  const int pg = tid >> 3;        // gather pixel 0..31
  const int ch = tid & 7;         // gather 8-ch chunk 0..7 (abs ch = ch*8)

  // XCD-aware swizzle: XCD (blockIdx%8) works one image (2 MB bf16 in L2).
  const int g8 = blockIdx.x & 7;
  const int slot = blockIdx.x >> 3;      // 0..255
  const int b = g8 >> 1;
  const int ti = (g8 & 1) * 256 + slot;  // 0..511: 32-px tile index
  const int h0 = ti >> 2;
  const int w0 = (ti & 3) * 32;
  const bf16* xb = xT + (size_t)b * HW * C;

  bf16x8 zero8;
#pragma unroll
  for (int j = 0; j < 8; ++j) zero8[j] = (bf16)0.f;

  // ============ conv: stage full-C window once, 18 MFMA k-steps ============
#pragma unroll
  for (int it = 0; it < 4; ++it) {  // 816 = 3 rows x 34 px x 8 chunks
    int id = it * 256 + tid;
    if (id < 816) {
      int chk = id & 7;
      int rest = id >> 3;
      int wp = rest % 34;
      int r = rest / 34;
      int yy = h0 + r - 1;
      int xx = w0 + wp - 1;
      bf16x8 v = zero8;
      if ((unsigned)yy < (unsigned)H && (unsigned)xx < (unsigned)W)
        v = *(const bf16x8*)(xb + (size_t)((yy << 7) + xx) * C + chk * 8);
      *(bf16x8*)(stage + soff(r * 34 + wp, chk)) = v;
    }
  }
  __syncthreads();
  f32x4 accC[2] = {{0.f,0.f,0.f,0.f},{0.f,0.f,0.f,0.f}};
  __builtin_amdgcn_s_setprio(1);
#pragma unroll 1
  for (int ph = 0; ph < 2; ++ph) {
#pragma unroll
    for (int kk = 0; kk < 9; ++kk) {
      // one a-frag load, used for both n-halves
      bf16x8 afr = *(const bf16x8*)(wfC +
          (size_t)(((ph * 9 + kk) * 4 + to) * 64 + lane) * 8);
#pragma unroll
      for (int nt = 0; nt < 2; ++nt) {
        int row = (kk / 3) * 34 + nt * 16 + n16 + kk % 3;
        bf16x8 bfr = *(const bf16x8*)(stage + soff(row, ph * 4 + q4));
        accC[nt] = __builtin_amdgcn_mfma_f32_16x16x32_bf16(afr, bfr, accC[nt], 0, 0, 0);
      }
    }
  }
  __builtin_amdgcn_s_setprio(0);
  __syncthreads();  // stage readers done before bufF overwrites

  // conv epilogue: bias + sigmoid -> bufF[p][o]
#pragma unroll
  for (int nt = 0; nt < 2; ++nt)
#pragma unroll
    for (int r = 0; r < 4; ++r) {
      int o = to * 16 + q4 * 4 + r;
      int p = nt * 16 + n16;
      float a = accC[nt][r];
      if (o < NOFF) {
        bufF[p * BSTR + o] = a + b_off[o];
      } else if (o < 54) {
        float s = a + b_mask[o - NOFF];
        bufF[p * BSTR + o] = 1.f / (1.f + __expf(-s));
      }
    }
  __syncthreads();

  // ----- bilinear precompute: 576 (p,gk) tasks -> packed 12B params -----
  // bufF [0,7040) and buf2 [12288,19200) are disjoint: compute+write direct,
  // single barrier at the end.
#pragma unroll
  for (int it = 0; it < 3; ++it) {
    int t = it * 256 + tid;
    if (t < 576) {
      int p = t & 31;
      int gk = t >> 5;
      int tap = gk % 9;
      float offy = bufF[p * BSTR + 2 * gk];
      float offx = bufF[p * BSTR + 2 * gk + 1];
      float m = bufF[p * BSTR + NOFF + gk];
      float py = offy + (float)(h0 + tap / 3 - 1);
      float px = offx + (float)(w0 + p + tap % 3 - 1);
      float y0f = floorf(py), x0f = floorf(px);
      float wy1 = py - y0f, wx1 = px - x0f;
      float wy0 = 1.f - wy1, wx0 = 1.f - wx1;
      int y0 = (int)y0f, x0 = (int)x0f;
      int y1 = y0 + 1, x1 = x0 + 1;
      bool y0ok = (unsigned)y0 < (unsigned)H, y1ok = (unsigned)y1 < (unsigned)H;
      bool x0ok = (unsigned)x0 < (unsigned)W, x1ok = (unsigned)x1 < (unsigned)W;
      float w00 = (y0ok && x0ok) ? wy0 * wx0 * m : 0.f;
      float w01 = (y0ok && x1ok) ? wy0 * wx1 * m : 0.f;
      float w10 = (y1ok && x0ok) ? wy1 * wx0 * m : 0.f;
      float w11 = (y1ok && x1ok) ? wy1 * wx1 * m : 0.f;
      unsigned int y0c = (unsigned)min(max(y0, 0), H - 1);
      unsigned int y1c = (unsigned)min(max(y1, 0), H - 1);
      unsigned int x0c = (unsigned)min(max(x0, 0), W - 1);
      unsigned int x1c = (unsigned)min(max(x1, 0), W - 1);
      int idx = p * 18 + gk;
      buf2a[idx] = (unsigned)f2h_bits(w00) | ((unsigned)f2h_bits(w01) << 16);
      buf2b[idx] = (unsigned)f2h_bits(w10) | ((unsigned)f2h_bits(w11) << 16);
      buf2c[idx] = y0c | (x0c << 8) | (y1c << 16) | (x1c << 24);
    }
  }
  __syncthreads();

  // -------- main deform: 3 tap-chunks, cooperative gather -> val -> MFMA ---
  f32x4 accM[2] = {{0.f,0.f,0.f,0.f},{0.f,0.f,0.f,0.f}};
  const bf16* bb = xb + ch * 8;   // this thread's 8-channel slice (abs)
  const int gg = ch >> 2;          // group of this chunk
#pragma unroll 1
  for (int kc = 0; kc < 3; ++kc) {
    if (kc) __syncthreads();  // val reuse vs previous MFMA readers
#pragma unroll
    for (int t = 0; t < 3; ++t) {  // 12 independent loads issued per thread
      int tap = kc * 3 + t;
      int idx = pg * 18 + gg * 9 + tap;
      unsigned wA = buf2a[idx];
      unsigned wB = buf2b[idx];
      unsigned co = buf2c[idx];
      float w00 = h2f(wA & 0xffff), w01 = h2f(wA >> 16);
      float w10 = h2f(wB & 0xffff), w11 = h2f(wB >> 16);
      int r0 = (int)(co & 255) << 7;
      int x0 = (int)((co >> 8) & 255);
      int r1 = (int)((co >> 16) & 255) << 7;
      int x1 = (int)(co >> 24);
      bf16x8 v00 = *(const bf16x8*)(bb + (size_t)(r0 + x0) * C);
      bf16x8 v01 = *(const bf16x8*)(bb + (size_t)(r0 + x1) * C);
      bf16x8 v10 = *(const bf16x8*)(bb + (size_t)(r1 + x0) * C);
      bf16x8 v11 = *(const bf16x8*)(bb + (size_t)(r1 + x1) * C);
      bf16x8 res;
#pragma unroll
      for (int j = 0; j < 8; ++j) {
        float v = (float)v00[j] * w00 + (float)v01[j] * w01 +
                  (float)v10[j] * w10 + (float)v11[j] * w11;
        res[j] = (bf16)v;
      }
      *(bf16x8*)(val + soff(t * 32 + pg, ch)) = res;
    }
    __syncthreads();
    __builtin_amdgcn_s_setprio(1);
#pragma unroll
    for (int t = 0; t < 3; ++t) {
      int tap = kc * 3 + t;
#pragma unroll
      for (int g = 0; g < 2; ++g) {
        // one a-frag load, used for both n-halves
        bf16x8 afr = *(const bf16x8*)(wfM + (size_t)g * WFRAG +
            (size_t)((tap * 4 + to) * 64 + lane) * 8);
#pragma unroll
        for (int nt = 0; nt < 2; ++nt) {
          int row = t * 32 + nt * 16 + n16;
          bf16x8 bfr = *(const bf16x8*)(val + soff(row, g * 4 + q4));
          accM[nt] = __builtin_amdgcn_mfma_f32_16x16x32_bf16(afr, bfr, accM[nt], 0, 0, 0);
        }
      }
    }
    __builtin_amdgcn_s_setprio(0);
  }

  // -------- epilogue: LDS transpose -> coalesced NCHW dwordx4 stores -------
  __syncthreads();  // val readers done before valF overwrites
#pragma unroll
  for (int nt = 0; nt < 2; ++nt)
#pragma unroll
    for (int r = 0; r < 4; ++r)
      valF[(to * 16 + q4 * 4 + r) * VSTR + nt * 16 + n16] = accM[nt][r];
  __syncthreads();
  {
    float* ob = out + (size_t)b * O * HW + (h0 << 7) + w0;
#pragma unroll
    for (int it = 0; it < 2; ++it) {
      int id = it * 256 + tid;
      int o = id >> 3, seg = id & 7;
      f32x4 v = *(f32x4*)&valF[o * VSTR + seg * 4];
      *(f32x4*)&ob[(size_t)o * HW + seg * 4] = v;
    }
  }
}

// ---------------------------------------------------------------------------
extern "C" void kernel_launch(void* const* d_in, const int* in_sizes, int n_in,
                              void* d_out, int out_size, void* d_ws,
                              size_t ws_size, hipStream_t stream) {
  const float* x = (const float*)d_in[0];
  const float* w_main = (const float*)d_in[1];
  const float* w_off = (const float*)d_in[2];
  const float* b_off = (const float*)d_in[3];
  const float* w_mask = (const float*)d_in[4];
  const float* b_mask = (const float*)d_in[5];
  float* out = (float*)d_out;

  unsigned short* xT16 = (unsigned short*)d_ws;     // 8,388,608 B
  bf16* wfC = (bf16*)(xT16 + (size_t)BB * HW * C);  // 73,728 B
  bf16* wfM = wfC + 36864;                          // 73,728 B

  prep_all<<<1024, 256, 0, stream>>>(x, w_main, w_off, w_mask, xT16, wfC, wfM);
  fused_deform<<<2048, 256, 0, stream>>>((const bf16*)xT16, wfC, wfM, b_off,
                                         b_mask, out);
}